// Round 3
// baseline (442.649 us; speedup 1.0000x reference)
//
#include <hip/hip_runtime.h>

// Shapes: B=4, C=16, D=16, W=32, DM=512, H=8, HD=64. 1024 slabs of 32 tokens.
// Sequence (b,h,c',d') <-> slab (b, c=2h+(c'>>3), d=2(c'&7)+(d'>>3)), j=d'&7:
//   tokens w = 4j..4j+3; position w' = (w&3)*8 + t uses qkv cols [t*192, t*192+192).
// vhat inverse: token (c,d,w), dm = t*64 + e from position w'=(w&3)*8+t of seq j=w>>2.
//
// R2: bf16 -> fp16 everywhere (same MFMA rate, 4x smaller quantization error).
// bf16 failed absmax 0.0322 vs 0.0228 — logit error ~8*sqrt(128)*dq*0.45 was the
// dominant term; fp16 cuts every input-quantization stage by 4x.

using f16x8 = __attribute__((ext_vector_type(8))) _Float16;
using f32x4 = __attribute__((ext_vector_type(4))) float;
using u16x4 = __attribute__((ext_vector_type(4))) unsigned short;

#define DEVI static __device__ __forceinline__

DEVI unsigned short f2h(float x) {            // fp32 -> fp16 RNE (v_cvt_f16_f32)
  _Float16 h = (_Float16)x;
  return *(unsigned short*)&h;
}

#define MFMA16(a, b, c) __builtin_amdgcn_mfma_f32_16x16x32_f16((a), (b), (c), 0, 0, 0)

// ---------------- weight prep: transpose + cast to fp16 [N][K] ----------------
__global__ void __launch_bounds__(256, 1)
prep_w(const float* __restrict__ Wqkv, const float* __restrict__ Wout,
       unsigned short* __restrict__ wq, unsigned short* __restrict__ wo)
{
  int tid = blockIdx.x * 256 + threadIdx.x;        // 4096*256 = 786432 + 262144 exactly
  if (tid < 512 * 1536) {
    int k = tid / 1536, n = tid - k * 1536;        // coalesced read of Wqkv[k][n]
    wq[n * 512 + k] = f2h(Wqkv[tid]);
  } else {
    int t2 = tid - 512 * 1536;
    int k = t2 >> 9, n = t2 & 511;
    wo[n * 512 + k] = f2h(Wout[t2]);
  }
}

// ---------------- fused LN + QKV + attention + out-proj ----------------
// LDS: qs/ks [seq][pos][72] (pad -> 2-way bank spread, 16B-aligned rows),
// vts [seq][e][48] (v transposed for PV B-operand), xv = union(xs, vh) [32][520].
struct __align__(16) SMem {
  unsigned short qs[8][32][72];   // 36864 B
  unsigned short ks[8][32][72];   // 36864 B
  unsigned short vts[8][64][48];  // 49152 B
  unsigned short xv[32][520];     // 33280 B  (xs during QKV, vh during out-proj)
};
static_assert(sizeof(SMem) == 156160, "LDS size");

__global__ void __launch_bounds__(256, 1)
fused_attn(const float* __restrict__ x, const float* __restrict__ gamma,
           const float* __restrict__ beta,
           const unsigned short* __restrict__ wq,   // [1536][512] fp16 (= W_qkv^T)
           const unsigned short* __restrict__ wo,   // [512][512]  fp16 (= W_out^T)
           const float* __restrict__ bout, float* __restrict__ out)
{
  __shared__ SMem sm;
  const int tid = threadIdx.x;
  const int wv  = tid >> 6;        // wave 0..3
  const int ln  = tid & 63;
  const int l15 = ln & 15;
  const int lg  = ln >> 4;         // lane group 0..3
  const size_t slab = blockIdx.x;  // ((b*16)+c)*16+d
  const float* xblk = x + slab * (32 * 512);

  // ---- Phase 1: LayerNorm -> xs (fp16) ----
  {
    const float4* gp = (const float4*)gamma;
    const float4* bp = (const float4*)beta;
    float4 g0 = gp[ln], g1 = gp[64 + ln];
    float4 b0 = bp[ln], b1 = bp[64 + ln];
    for (int i = 0; i < 8; ++i) {
      int w = wv * 8 + i;
      const float4* xp = (const float4*)(xblk + w * 512);
      float4 v0 = xp[ln], v1 = xp[64 + ln];
      float s  = v0.x + v0.y + v0.z + v0.w + v1.x + v1.y + v1.z + v1.w;
      float s2 = v0.x*v0.x + v0.y*v0.y + v0.z*v0.z + v0.w*v0.w
               + v1.x*v1.x + v1.y*v1.y + v1.z*v1.z + v1.w*v1.w;
      #pragma unroll
      for (int d2 = 1; d2 < 64; d2 <<= 1) {
        s  += __shfl_xor(s, d2);
        s2 += __shfl_xor(s2, d2);
      }
      float mean = s * (1.f / 512.f);
      float var  = s2 * (1.f / 512.f) - mean * mean;
      float rstd = rsqrtf(var + 1e-5f);
      u16x4 o0, o1;
      o0.x = f2h((v0.x - mean) * rstd * g0.x + b0.x);
      o0.y = f2h((v0.y - mean) * rstd * g0.y + b0.y);
      o0.z = f2h((v0.z - mean) * rstd * g0.z + b0.z);
      o0.w = f2h((v0.w - mean) * rstd * g0.w + b0.w);
      o1.x = f2h((v1.x - mean) * rstd * g1.x + b1.x);
      o1.y = f2h((v1.y - mean) * rstd * g1.y + b1.y);
      o1.z = f2h((v1.z - mean) * rstd * g1.z + b1.z);
      o1.w = f2h((v1.w - mean) * rstd * g1.w + b1.w);
      *(u16x4*)&sm.xv[w][ln * 4]       = o0;
      *(u16x4*)&sm.xv[w][256 + ln * 4] = o1;
    }
  }
  __syncthreads();

  // ---- Phase 2: QKV GEMM, per-wave N-slice of 384 in 3 passes of 128 ----
  for (int p = 0; p < 3; ++p) {
    const int nb = wv * 384 + p * 128;
    f32x4 acc[2][8];
    const f32x4 zz = {0.f, 0.f, 0.f, 0.f};
    #pragma unroll
    for (int a_ = 0; a_ < 2; ++a_)
      #pragma unroll
      for (int b_ = 0; b_ < 8; ++b_) acc[a_][b_] = zz;
    #pragma unroll
    for (int k = 0; k < 16; ++k) {
      f16x8 a0 = *(const f16x8*)&sm.xv[l15][k * 32 + lg * 8];
      f16x8 a1 = *(const f16x8*)&sm.xv[l15 + 16][k * 32 + lg * 8];
      #pragma unroll
      for (int nf = 0; nf < 8; ++nf) {
        const int n = nb + nf * 16 + l15;
        f16x8 bb = *(const f16x8*)&wq[(size_t)n * 512 + k * 32 + lg * 8];
        acc[0][nf] = MFMA16(a0, bb, acc[0][nf]);
        acc[1][nf] = MFMA16(a1, bb, acc[1][nf]);
      }
    }
    // epilogue: scatter D frags (col = l15, rows = lg*4+r+16*mf) into qs/ks/vts
    #pragma unroll
    for (int mf = 0; mf < 2; ++mf) {
      const int sq = lg + 4 * mf;               // seq = w>>2, w = lg*4+r+16*mf
      #pragma unroll
      for (int nf = 0; nf < 8; ++nf) {
        const int n = nb + nf * 16 + l15;
        const int t = n / 192;
        const int off = n - t * 192;            // frag's 16 cols never cross a 64-seg
        #pragma unroll
        for (int r = 0; r < 4; ++r) {
          const unsigned short bv = f2h(acc[mf][nf][r]);
          const int pos = r * 8 + t;            // w&3 == r
          if (off < 64)       sm.qs[sq][pos][off]            = bv;
          else if (off < 128) sm.ks[sq][pos][off - 64]       = bv;
          else                sm.vts[sq][off - 128][pos]     = bv;
        }
      }
    }
  }
  __syncthreads();

  // ---- Phase 3: attention, 2 sequences per wave ----
  unsigned short* ps = &sm.qs[wv * 2][0][0];    // [32][40] overlay on dead q-buffer
  for (int i = 0; i < 2; ++i) {
    const int sq = wv * 2 + i;
    const unsigned short* qb = &sm.qs[sq][0][0];
    const unsigned short* kb = &sm.ks[sq][0][0];
    const unsigned short* vb = &sm.vts[sq][0][0];
    const f32x4 zz = {0.f, 0.f, 0.f, 0.f};
    f32x4 sc[2][2] = {{zz, zz}, {zz, zz}};
    #pragma unroll
    for (int k2 = 0; k2 < 2; ++k2) {            // K=64 over e
      f16x8 a0 = *(const f16x8*)&qb[l15 * 72 + k2 * 32 + lg * 8];
      f16x8 a1 = *(const f16x8*)&qb[(l15 + 16) * 72 + k2 * 32 + lg * 8];
      f16x8 b0 = *(const f16x8*)&kb[l15 * 72 + k2 * 32 + lg * 8];
      f16x8 b1 = *(const f16x8*)&kb[(l15 + 16) * 72 + k2 * 32 + lg * 8];
      sc[0][0] = MFMA16(a0, b0, sc[0][0]);
      sc[0][1] = MFMA16(a0, b1, sc[0][1]);
      sc[1][0] = MFMA16(a1, b0, sc[1][0]);
      sc[1][1] = MFMA16(a1, b1, sc[1][1]);
    }
    // softmax over 32 cols; row r lives in one 16-lane group (cols l15, l15+16)
    #pragma unroll
    for (int mf = 0; mf < 2; ++mf) {
      #pragma unroll
      for (int r = 0; r < 4; ++r) {
        float s0 = sc[mf][0][r] * 8.f;          // reference MULTIPLIES by sqrt(64)
        float s1 = sc[mf][1][r] * 8.f;
        float m = fmaxf(s0, s1);
        #pragma unroll
        for (int d2 = 1; d2 < 16; d2 <<= 1) m = fmaxf(m, __shfl_xor(m, d2));
        float p0 = expf(s0 - m), p1 = expf(s1 - m);
        float sum = p0 + p1;
        #pragma unroll
        for (int d2 = 1; d2 < 16; d2 <<= 1) sum += __shfl_xor(sum, d2);
        float inv = 1.f / sum;
        const int row = lg * 4 + r + 16 * mf;
        ps[row * 40 + l15]      = f2h(p0 * inv);
        ps[row * 40 + l15 + 16] = f2h(p1 * inv);
      }
    }
    // PV: A = P (via LDS transpose), B = V^T rows -> 16B contiguous reads
    f32x4 ov[2][4] = {{zz, zz, zz, zz}, {zz, zz, zz, zz}};
    f16x8 pa0 = *(const f16x8*)&ps[l15 * 40 + lg * 8];
    f16x8 pa1 = *(const f16x8*)&ps[(l15 + 16) * 40 + lg * 8];
    #pragma unroll
    for (int nf = 0; nf < 4; ++nf) {
      f16x8 bb = *(const f16x8*)&vb[(nf * 16 + l15) * 48 + lg * 8];
      ov[0][nf] = MFMA16(pa0, bb, ov[0][nf]);
      ov[1][nf] = MFMA16(pa1, bb, ov[1][nf]);
    }
    // scatter vhat -> vh rows (tokens 4sq..4sq+3), dm = (w'&7)*64 + e
    #pragma unroll
    for (int mf = 0; mf < 2; ++mf)
      #pragma unroll
      for (int nf = 0; nf < 4; ++nf)
        #pragma unroll
        for (int r = 0; r < 4; ++r) {
          const int wp = lg * 4 + r + 16 * mf;
          const int e  = nf * 16 + l15;
          sm.xv[4 * sq + (wp >> 3)][(wp & 7) * 64 + e] = f2h(ov[mf][nf][r]);
        }
  }
  __syncthreads();

  // ---- Phase 4: out-proj [32x512]*[512x512] + bias, per-wave N-slice 128 ----
  {
    const int nb = wv * 128;
    const f32x4 zz = {0.f, 0.f, 0.f, 0.f};
    f32x4 oa[2][8];
    #pragma unroll
    for (int a_ = 0; a_ < 2; ++a_)
      #pragma unroll
      for (int b_ = 0; b_ < 8; ++b_) oa[a_][b_] = zz;
    #pragma unroll
    for (int k = 0; k < 16; ++k) {
      f16x8 a0 = *(const f16x8*)&sm.xv[l15][k * 32 + lg * 8];
      f16x8 a1 = *(const f16x8*)&sm.xv[l15 + 16][k * 32 + lg * 8];
      #pragma unroll
      for (int nf = 0; nf < 8; ++nf) {
        const int n = nb + nf * 16 + l15;
        f16x8 bb = *(const f16x8*)&wo[(size_t)n * 512 + k * 32 + lg * 8];
        oa[0][nf] = MFMA16(a0, bb, oa[0][nf]);
        oa[1][nf] = MFMA16(a1, bb, oa[1][nf]);
      }
    }
    float* outp = out + slab * (32 * 512);
    #pragma unroll
    for (int nf = 0; nf < 8; ++nf) {
      const int n = nb + nf * 16 + l15;
      const float bias = bout[n];
      #pragma unroll
      for (int mf = 0; mf < 2; ++mf)
        #pragma unroll
        for (int r = 0; r < 4; ++r) {
          const int w = lg * 4 + r + 16 * mf;
          outp[(size_t)w * 512 + n] = oa[mf][nf][r] + bias;
        }
    }
  }
}

extern "C" void kernel_launch(void* const* d_in, const int* in_sizes, int n_in,
                              void* d_out, int out_size, void* d_ws, size_t ws_size,
                              hipStream_t stream) {
  const float* x     = (const float*)d_in[0];
  const float* gamma = (const float*)d_in[1];
  const float* beta  = (const float*)d_in[2];
  const float* Wqkv  = (const float*)d_in[3];
  const float* Wout  = (const float*)d_in[4];
  const float* bout  = (const float*)d_in[5];
  float* out = (float*)d_out;

  unsigned short* wq = (unsigned short*)d_ws;          // 1536*512 fp16
  unsigned short* wo = wq + 1536 * 512;                // 512*512 fp16

  prep_w<<<4096, 256, 0, stream>>>(Wqkv, Wout, wq, wo);
  fused_attn<<<1024, 256, 0, stream>>>(x, gamma, beta, wq, wo, bout, out);
}

// Round 5
// 379.512 us; speedup vs baseline: 1.1664x; 1.1664x over previous
//
#include <hip/hip_runtime.h>

// Shapes: B=4, C=16, D=16, W=32, DM=512, H=8, HD=64. 1024 slabs of 32 tokens.
// Sequence (b,h,c',d') <-> slab (b, c=2h+(c'>>3), d=2(c'&7)+(d'>>3)), j=d'&7:
//   tokens w = 4j..4j+3; position w' = (w&3)*8 + t uses qkv cols [t*192, t*192+192).
// vhat inverse: token (c,d,w), dm = t*64 + e from position w'=(w&3)*8+t of seq j=w>>2.
//
// R2: bf16 -> fp16 (absmax 0.0322 -> 0.0039, passes).
// R3 counters: Occ 11.8% (1 wave/SIMD), MfmaUtil 8%, HBM 4.6% -> latency-bound.
// R4: 512-thread blocks (2 waves/SIMD), depth-2 B-frag prefetch, LDS-tiled prep_w.

using f16x8 = __attribute__((ext_vector_type(8))) _Float16;
using f32x4 = __attribute__((ext_vector_type(4))) float;
using u16x4 = __attribute__((ext_vector_type(4))) unsigned short;

#define DEVI static __device__ __forceinline__

DEVI unsigned short f2h(float x) {            // fp32 -> fp16 RNE (v_cvt_f16_f32)
  _Float16 h = (_Float16)x;
  return *(unsigned short*)&h;
}

#define MFMA16(a, b, c) __builtin_amdgcn_mfma_f32_16x16x32_f16((a), (b), (c), 0, 0, 0)

// -------- weight prep: LDS-tiled 64x64 transpose, fp32 -> fp16 [N][K] --------
// 192 blocks for Wqkv (8 kt x 24 nt) + 64 blocks for Wout (8 x 8).
__global__ void __launch_bounds__(256, 1)
prep_w(const float* __restrict__ Wqkv, const float* __restrict__ Wout,
       unsigned short* __restrict__ wq, unsigned short* __restrict__ wo)
{
  __shared__ float t[64][68];
  const int tid = threadIdx.x;
  const int b = blockIdx.x;
  const float* src; unsigned short* dst; int ldsrc, kt, nt;
  if (b < 192) { kt = b / 24; nt = b % 24; src = Wqkv; dst = wq; ldsrc = 1536; }
  else { int b2 = b - 192; kt = b2 >> 3; nt = b2 & 7; src = Wout; dst = wo; ldsrc = 512; }
  const int r = tid >> 4, c4 = (tid & 15) * 4;
  #pragma unroll
  for (int it = 0; it < 4; ++it) {          // coalesced float4 reads
    int row = it * 16 + r;
    float4 v = *(const float4*)&src[(size_t)(kt * 64 + row) * ldsrc + nt * 64 + c4];
    *(float4*)&t[row][c4] = v;
  }
  __syncthreads();
  #pragma unroll
  for (int it = 0; it < 4; ++it) {          // coalesced 8B fp16 writes (128B/row)
    int n = it * 16 + r;
    u16x4 o;
    o.x = f2h(t[c4 + 0][n]); o.y = f2h(t[c4 + 1][n]);
    o.z = f2h(t[c4 + 2][n]); o.w = f2h(t[c4 + 3][n]);
    *(u16x4*)&dst[(size_t)(nt * 64 + n) * 512 + kt * 64 + c4] = o;
  }
}

// ---------------- fused LN + QKV + attention + out-proj ----------------
// LDS: qs/ks [seq][pos][72] (pad -> bank spread, 16B-aligned rows),
// vts [seq][e][48] (v transposed for PV B-operand), xv = union(xs, vh) [32][520].
struct __align__(16) SMem {
  unsigned short qs[8][32][72];   // 36864 B
  unsigned short ks[8][32][72];   // 36864 B
  unsigned short vts[8][64][48];  // 49152 B
  unsigned short xv[32][520];     // 33280 B  (xs during QKV, vh during out-proj)
};
static_assert(sizeof(SMem) == 156160, "LDS size");

__global__ void __launch_bounds__(512, 1)
fused_attn(const float* __restrict__ x, const float* __restrict__ gamma,
           const float* __restrict__ beta,
           const unsigned short* __restrict__ wq,   // [1536][512] fp16 (= W_qkv^T)
           const unsigned short* __restrict__ wo,   // [512][512]  fp16 (= W_out^T)
           const float* __restrict__ bout, float* __restrict__ out)
{
  __shared__ SMem sm;
  const int tid = threadIdx.x;
  const int wv  = tid >> 6;        // wave 0..7
  const int ln  = tid & 63;
  const int l15 = ln & 15;
  const int lg  = ln >> 4;         // lane group 0..3
  const size_t slab = blockIdx.x;  // ((b*16)+c)*16+d
  const float* xblk = x + slab * (32 * 512);
  const f32x4 zz = {0.f, 0.f, 0.f, 0.f};

  // ---- Phase 1: LayerNorm -> xs (fp16), 4 tokens per wave ----
  {
    const float4* gp = (const float4*)gamma;
    const float4* bp = (const float4*)beta;
    float4 g0 = gp[ln], g1 = gp[64 + ln];
    float4 b0 = bp[ln], b1 = bp[64 + ln];
    for (int i = 0; i < 4; ++i) {
      int w = wv * 4 + i;
      const float4* xp = (const float4*)(xblk + w * 512);
      float4 v0 = xp[ln], v1 = xp[64 + ln];
      float s  = v0.x + v0.y + v0.z + v0.w + v1.x + v1.y + v1.z + v1.w;
      float s2 = v0.x*v0.x + v0.y*v0.y + v0.z*v0.z + v0.w*v0.w
               + v1.x*v1.x + v1.y*v1.y + v1.z*v1.z + v1.w*v1.w;
      #pragma unroll
      for (int d2 = 1; d2 < 64; d2 <<= 1) {
        s  += __shfl_xor(s, d2);
        s2 += __shfl_xor(s2, d2);
      }
      float mean = s * (1.f / 512.f);
      float var  = s2 * (1.f / 512.f) - mean * mean;
      float rstd = rsqrtf(var + 1e-5f);
      u16x4 o0, o1;
      o0.x = f2h((v0.x - mean) * rstd * g0.x + b0.x);
      o0.y = f2h((v0.y - mean) * rstd * g0.y + b0.y);
      o0.z = f2h((v0.z - mean) * rstd * g0.z + b0.z);
      o0.w = f2h((v0.w - mean) * rstd * g0.w + b0.w);
      o1.x = f2h((v1.x - mean) * rstd * g1.x + b1.x);
      o1.y = f2h((v1.y - mean) * rstd * g1.y + b1.y);
      o1.z = f2h((v1.z - mean) * rstd * g1.z + b1.z);
      o1.w = f2h((v1.w - mean) * rstd * g1.w + b1.w);
      *(u16x4*)&sm.xv[w][ln * 4]       = o0;
      *(u16x4*)&sm.xv[w][256 + ln * 4] = o1;
    }
  }
  __syncthreads();

  // ---- Phase 2: QKV GEMM, 192 cols/wave in 3 chunks of 64, depth-2 prefetch ----
  for (int c = 0; c < 3; ++c) {
    const int nb = wv * 192 + c * 64;
    f32x4 acc[2][4];
    #pragma unroll
    for (int a_ = 0; a_ < 2; ++a_)
      #pragma unroll
      for (int b_ = 0; b_ < 4; ++b_) acc[a_][b_] = zz;
    f16x8 bb[3][4];
    #pragma unroll
    for (int nf = 0; nf < 4; ++nf)
      bb[0][nf] = *(const f16x8*)&wq[(size_t)(nb + nf * 16 + l15) * 512 + lg * 8];
    #pragma unroll
    for (int nf = 0; nf < 4; ++nf)
      bb[1][nf] = *(const f16x8*)&wq[(size_t)(nb + nf * 16 + l15) * 512 + 32 + lg * 8];
    #pragma unroll
    for (int k = 0; k < 16; ++k) {
      if (k < 14) {
        #pragma unroll
        for (int nf = 0; nf < 4; ++nf)
          bb[(k + 2) % 3][nf] =
            *(const f16x8*)&wq[(size_t)(nb + nf * 16 + l15) * 512 + (k + 2) * 32 + lg * 8];
      }
      f16x8 a0 = *(const f16x8*)&sm.xv[l15][k * 32 + lg * 8];
      f16x8 a1 = *(const f16x8*)&sm.xv[l15 + 16][k * 32 + lg * 8];
      #pragma unroll
      for (int nf = 0; nf < 4; ++nf) {
        acc[0][nf] = MFMA16(a0, bb[k % 3][nf], acc[0][nf]);
        acc[1][nf] = MFMA16(a1, bb[k % 3][nf], acc[1][nf]);
      }
    }
    // epilogue: scatter D frags (col = l15, rows = lg*4+r+16*mf) into qs/ks/vts
    #pragma unroll
    for (int mf = 0; mf < 2; ++mf) {
      #pragma unroll
      for (int nf = 0; nf < 4; ++nf) {
        const int n = nb + nf * 16 + l15;
        const int t = n / 192;
        const int off = n - t * 192;            // frag's 16 cols never cross a 64-seg
        const int sq = lg + 4 * mf;             // seq = w>>2, w = lg*4+r+16*mf
        #pragma unroll
        for (int r = 0; r < 4; ++r) {
          const unsigned short bv = f2h(acc[mf][nf][r]);
          const int pos = r * 8 + t;            // w&3 == r
          if (off < 64)       sm.qs[sq][pos][off]            = bv;
          else if (off < 128) sm.ks[sq][pos][off - 64]       = bv;
          else                sm.vts[sq][off - 128][pos]     = bv;
        }
      }
    }
  }
  __syncthreads();

  // ---- Phase 3: attention, 1 sequence per wave ----
  {
    const int sq = wv;
    unsigned short* ps = &sm.qs[sq][0][0];      // [32][40] overlay on dead q-buffer
    const unsigned short* qb = &sm.qs[sq][0][0];
    const unsigned short* kb = &sm.ks[sq][0][0];
    const unsigned short* vb = &sm.vts[sq][0][0];
    f32x4 sc[2][2] = {{zz, zz}, {zz, zz}};
    #pragma unroll
    for (int k2 = 0; k2 < 2; ++k2) {            // K=64 over e
      f16x8 a0 = *(const f16x8*)&qb[l15 * 72 + k2 * 32 + lg * 8];
      f16x8 a1 = *(const f16x8*)&qb[(l15 + 16) * 72 + k2 * 32 + lg * 8];
      f16x8 b0 = *(const f16x8*)&kb[l15 * 72 + k2 * 32 + lg * 8];
      f16x8 b1 = *(const f16x8*)&kb[(l15 + 16) * 72 + k2 * 32 + lg * 8];
      sc[0][0] = MFMA16(a0, b0, sc[0][0]);
      sc[0][1] = MFMA16(a0, b1, sc[0][1]);
      sc[1][0] = MFMA16(a1, b0, sc[1][0]);
      sc[1][1] = MFMA16(a1, b1, sc[1][1]);
    }
    // softmax over 32 cols; row r lives in one 16-lane group (cols l15, l15+16)
    #pragma unroll
    for (int mf = 0; mf < 2; ++mf) {
      #pragma unroll
      for (int r = 0; r < 4; ++r) {
        float s0 = sc[mf][0][r] * 8.f;          // reference MULTIPLIES by sqrt(64)
        float s1 = sc[mf][1][r] * 8.f;
        float m = fmaxf(s0, s1);
        #pragma unroll
        for (int d2 = 1; d2 < 16; d2 <<= 1) m = fmaxf(m, __shfl_xor(m, d2));
        float p0 = expf(s0 - m), p1 = expf(s1 - m);
        float sum = p0 + p1;
        #pragma unroll
        for (int d2 = 1; d2 < 16; d2 <<= 1) sum += __shfl_xor(sum, d2);
        float inv = 1.f / sum;
        const int row = lg * 4 + r + 16 * mf;
        ps[row * 40 + l15]      = f2h(p0 * inv);
        ps[row * 40 + l15 + 16] = f2h(p1 * inv);
      }
    }
    // PV: A = P (via LDS transpose), B = V^T rows -> 16B contiguous reads
    f32x4 ov[2][4] = {{zz, zz, zz, zz}, {zz, zz, zz, zz}};
    f16x8 pa0 = *(const f16x8*)&ps[l15 * 40 + lg * 8];
    f16x8 pa1 = *(const f16x8*)&ps[(l15 + 16) * 40 + lg * 8];
    #pragma unroll
    for (int nf = 0; nf < 4; ++nf) {
      f16x8 bb = *(const f16x8*)&vb[(nf * 16 + l15) * 48 + lg * 8];
      ov[0][nf] = MFMA16(pa0, bb, ov[0][nf]);
      ov[1][nf] = MFMA16(pa1, bb, ov[1][nf]);
    }
    // scatter vhat -> vh rows (tokens 4sq..4sq+3), dm = (w'&7)*64 + e
    #pragma unroll
    for (int mf = 0; mf < 2; ++mf)
      #pragma unroll
      for (int nf = 0; nf < 4; ++nf)
        #pragma unroll
        for (int r = 0; r < 4; ++r) {
          const int wp = lg * 4 + r + 16 * mf;
          const int e  = nf * 16 + l15;
          sm.xv[4 * sq + (wp >> 3)][(wp & 7) * 64 + e] = f2h(ov[mf][nf][r]);
        }
  }
  __syncthreads();

  // ---- Phase 4: out-proj, 64 cols/wave, depth-2 prefetch ----
  {
    const int nb = wv * 64;
    f32x4 oa[2][4];
    #pragma unroll
    for (int a_ = 0; a_ < 2; ++a_)
      #pragma unroll
      for (int b_ = 0; b_ < 4; ++b_) oa[a_][b_] = zz;
    f16x8 bb[3][4];
    #pragma unroll
    for (int nf = 0; nf < 4; ++nf)
      bb[0][nf] = *(const f16x8*)&wo[(size_t)(nb + nf * 16 + l15) * 512 + lg * 8];
    #pragma unroll
    for (int nf = 0; nf < 4; ++nf)
      bb[1][nf] = *(const f16x8*)&wo[(size_t)(nb + nf * 16 + l15) * 512 + 32 + lg * 8];
    #pragma unroll
    for (int k = 0; k < 16; ++k) {
      if (k < 14) {
        #pragma unroll
        for (int nf = 0; nf < 4; ++nf)
          bb[(k + 2) % 3][nf] =
            *(const f16x8*)&wo[(size_t)(nb + nf * 16 + l15) * 512 + (k + 2) * 32 + lg * 8];
      }
      f16x8 a0 = *(const f16x8*)&sm.xv[l15][k * 32 + lg * 8];
      f16x8 a1 = *(const f16x8*)&sm.xv[l15 + 16][k * 32 + lg * 8];
      #pragma unroll
      for (int nf = 0; nf < 4; ++nf) {
        oa[0][nf] = MFMA16(a0, bb[k % 3][nf], oa[0][nf]);
        oa[1][nf] = MFMA16(a1, bb[k % 3][nf], oa[1][nf]);
      }
    }
    float* outp = out + slab * (32 * 512);
    #pragma unroll
    for (int nf = 0; nf < 4; ++nf) {
      const int n = nb + nf * 16 + l15;
      const float bias = bout[n];
      #pragma unroll
      for (int mf = 0; mf < 2; ++mf)
        #pragma unroll
        for (int r = 0; r < 4; ++r) {
          const int w = lg * 4 + r + 16 * mf;
          outp[(size_t)w * 512 + n] = oa[mf][nf][r] + bias;
        }
    }
  }
}

extern "C" void kernel_launch(void* const* d_in, const int* in_sizes, int n_in,
                              void* d_out, int out_size, void* d_ws, size_t ws_size,
                              hipStream_t stream) {
  const float* x     = (const float*)d_in[0];
  const float* gamma = (const float*)d_in[1];
  const float* beta  = (const float*)d_in[2];
  const float* Wqkv  = (const float*)d_in[3];
  const float* Wout  = (const float*)d_in[4];
  const float* bout  = (const float*)d_in[5];
  float* out = (float*)d_out;

  unsigned short* wq = (unsigned short*)d_ws;          // 1536*512 fp16
  unsigned short* wo = wq + 1536 * 512;                // 512*512 fp16

  prep_w<<<256, 256, 0, stream>>>(Wqkv, Wout, wq, wo);
  fused_attn<<<1024, 512, 0, stream>>>(x, gamma, beta, wq, wo, bout, out);
}